// Round 5
// baseline (155.300 us; speedup 1.0000x reference)
//
#include <hip/hip_runtime.h>
#include <hip/hip_bf16.h>

#define BN 4
#define CN 64
#define ON 64
#define HN 128
#define WN 128
#define HWN (HN*WN)
#define NT 9

typedef __attribute__((ext_vector_type(8))) short bf16x8;
typedef __attribute__((ext_vector_type(4))) float floatx4;

static __device__ __forceinline__ unsigned short f2bf(float f) {
    unsigned int u = __builtin_bit_cast(unsigned int, f);
    u += 0x7fffu + ((u >> 16) & 1u);   // RNE
    return (unsigned short)(u >> 16);
}
static __device__ __forceinline__ float bf2f(short h) {
    unsigned int u = ((unsigned int)(unsigned short)h) << 16;
    return __builtin_bit_cast(float, u);
}

// XCD-aware swizzle for 1024 blocks: XCD k owns works [k*128, k*128+128)
// = 64 consecutive rows of one image (bf16 slice ~1.05MB < 4MB L2/XCD).
static __device__ __forceinline__ int swz_work(int b) {
    return ((b & 7) << 7) | (b >> 3);
}

// ---------------------------------------------------------------------------
// Kernel T: x (B,C,H,W) f32 -> xTh (B,H,W,C) bf16 (channel-contiguous).
// ---------------------------------------------------------------------------
__global__ __launch_bounds__(256) void transpose_kernel(
    const float* __restrict__ x, unsigned short* __restrict__ xTh)
{
    __shared__ float ls[64][65];
    const int tid   = threadIdx.x;
    const int work  = swz_work(blockIdx.x);
    const int pbase = work << 6;
    const int bi    = pbase >> 14;
    const int poff  = pbase & (HWN-1);
    const float* xb = x + (size_t)bi*CN*HWN + poff;
    const int lane = tid & 63, g = tid >> 6;

    #pragma unroll
    for (int k = 0; k < 16; ++k) {
        int c = g*16 + k;
        ls[c][lane] = xb[(size_t)c*HWN + lane];   // coalesced 256B per instr
    }
    __syncthreads();

    unsigned short* dst = xTh + (size_t)pbase*CN;
    #pragma unroll
    for (int j = 0; j < 2; ++j) {
        int u   = j*256 + tid;        // uint4 index, 512 total (8 ch each)
        int p   = u >> 3;
        int c8i = (u & 7)*8;
        unsigned int a = (unsigned int)f2bf(ls[c8i+0][p]) | ((unsigned int)f2bf(ls[c8i+1][p])<<16);
        unsigned int b = (unsigned int)f2bf(ls[c8i+2][p]) | ((unsigned int)f2bf(ls[c8i+3][p])<<16);
        unsigned int c = (unsigned int)f2bf(ls[c8i+4][p]) | ((unsigned int)f2bf(ls[c8i+5][p])<<16);
        unsigned int e = (unsigned int)f2bf(ls[c8i+6][p]) | ((unsigned int)f2bf(ls[c8i+7][p])<<16);
        ((uint4*)dst)[u] = make_uint4(a,b,c,e);
    }
}

// ---------------------------------------------------------------------------
// Tiny kernel: w_conv (O,C,3,3) f32 -> wbf[n][o][c] bf16 for MFMA B-frags.
// ---------------------------------------------------------------------------
__global__ __launch_bounds__(256) void wbf_kernel(
    const float* __restrict__ w_conv, unsigned short* __restrict__ wbf)
{
    int gid = blockIdx.x * 256 + threadIdx.x;
    if (gid < ON*CN*NT) {
        int o   = gid / (CN*NT);
        int rem = gid - o*(CN*NT);
        int c   = rem / NT;
        int n   = rem - c*NT;
        wbf[(n*ON + o)*CN + c] = f2bf(w_conv[gid]);
    }
}

// ---------------------------------------------------------------------------
// Fused kernel: 64 pixels/block, 4 waves, wave g owns pixels g*16..g*16+15.
// Everything wave-private -> no barriers in the main loop.
//   conv (from xTh, 8pix x 8chgrp lanes) -> shfl reduce -> Hom -> taps (LDS)
//   9 phases: bilinear gather (bf16, 8 loads/lane) -> sT -> MFMA vs wbf
// ---------------------------------------------------------------------------
#define LDSF 23040  // swofft 2304 | tapB 2304 | tapW 9216 | sT 9216

__global__ __launch_bounds__(256) void fused_deform(
    const unsigned short* __restrict__ xTh, const float* __restrict__ w_off,
    const float* __restrict__ P, const float* __restrict__ d,
    const float* __restrict__ Pinv,
    const unsigned short* __restrict__ wbf, float* __restrict__ out)
{
    __shared__ __align__(16) char lds[LDSF];
    float*          swofft = (float*)lds;                    // [9][64] w_off^T
    int*            tapB   = (int*)(lds + 2304);             // [576] ushort-unit base
    float4*         tapW   = (float4*)(lds + 4608);          // [576]
    unsigned short* sT     = (unsigned short*)(lds + 13824); // [64][72]

    const int tid  = threadIdx.x;
    const int lane = tid & 63;
    const int g    = tid >> 6;

    // w_off (C,3,3) -> swofft[n][c]
    for (int i = tid; i < CN*NT; i += 256) {
        int n = i >> 6, c = i & 63;
        swofft[i] = w_off[c*NT + n];
    }

    const int work  = swz_work(blockIdx.x);
    const int pbase = work << 6;
    const int w0    = pbase & (WN-1);
    const int hi    = (pbase >> 7) & (HN-1);
    const int bi    = pbase >> 14;
    const unsigned short* xb = xTh + (size_t)bi * HWN * CN;

    __syncthreads();                       // swofft ready

    // ---- conv: lane = (c8 chan-group)*8 + (p8 pixel); 2 iters cover 16 pix
    const int p8 = lane & 7;
    const int c8 = lane >> 3;
    float r0 = 0.f, r1 = 0.f;
    #pragma unroll
    for (int i = 0; i < 2; ++i) {
        int bp = g*16 + i*8 + p8;
        int wi = w0 + bp;
        float racc = 0.f;
        #pragma unroll
        for (int ky = 0; ky < 3; ++ky) {
            int yy = hi + ky - 1;
            bool rok = (yy >= 0) && (yy < HN);
            int yc = min(max(yy,0), HN-1);
            #pragma unroll
            for (int kx = 0; kx < 3; ++kx) {
                int xx = wi + kx - 1;
                bool ok = rok && (xx >= 0) && (xx < WN);
                int xc = min(max(xx,0), WN-1);
                float m = ok ? 1.f : 0.f;
                bf16x8 v = *(const bf16x8*)(xb + (size_t)(yc*WN + xc)*CN + c8*8);
                int n = ky*3 + kx;
                const float4* wv = (const float4*)&swofft[n*64 + c8*8];
                float4 wa = wv[0], wb = wv[1];
                float s;
                s = bf2f(v[0])*wa.x;
                s = fmaf(bf2f(v[1]), wa.y, s);
                s = fmaf(bf2f(v[2]), wa.z, s);
                s = fmaf(bf2f(v[3]), wa.w, s);
                s = fmaf(bf2f(v[4]), wb.x, s);
                s = fmaf(bf2f(v[5]), wb.y, s);
                s = fmaf(bf2f(v[6]), wb.z, s);
                s = fmaf(bf2f(v[7]), wb.w, s);
                racc = fmaf(m, s, racc);
            }
        }
        if (i == 0) r0 = racc; else r1 = racc;
    }
    #pragma unroll
    for (int off = 8; off < 64; off <<= 1) {
        r0 += __shfl_xor(r0, off);
        r1 += __shfl_xor(r1, off);
    }
    // After the butterfly over lane bits 3-5, EVERY lane holds the full
    // 64-channel sum for pixel g*16+p8 in r0 and g*16+8+p8 in r1. The pixel
    // this lane's Hom needs is g*16 + (lane&15) = g*16 + (lane&7) + (lane&8)
    // -> pure per-lane select. (R4 bug: __shfl from exec-masked-off lanes in
    // a divergent ternary returns undefined data on CDNA ds_bpermute.)
    float praw = ((lane & 8) == 0) ? r0 : r1;

    // ---- hom + taps: lane works on pixel (lane&15), n-subset (lane>>4)
    {
        const int mypix = lane & 15;
        const int bp    = g*16 + mypix;
        float lw = fminf(fmaxf(praw + 0.5f, 0.f), 1.f);
        float pw0 = exp2f(lw * log2f(d[0]));
        float pw1 = exp2f(lw * log2f(d[1]));
        float pw2 = exp2f(lw * log2f(d[2]));
        float Hm[9];
        #pragma unroll
        for (int i = 0; i < 3; ++i)
            #pragma unroll
            for (int j = 0; j < 3; ++j)
                Hm[i*3+j] = P[i*3+0]*pw0*Pinv[0+j]
                          + P[i*3+1]*pw1*Pinv[3+j]
                          + P[i*3+2]*pw2*Pinv[6+j];
        for (int n = lane >> 4; n < NT; n += 4) {
            float fx = (float)(n % 3) - 1.f;
            float fy = (float)(n / 3) - 1.f;
            float qx = Hm[0]*fx + Hm[1]*fy + Hm[2];
            float qy = Hm[3]*fx + Hm[4]*fy + Hm[5];
            float qz = Hm[6]*fx + Hm[7]*fy + Hm[8];
            float ri = 1.f / qz;
            float px = (float)(w0 + bp) + qx*ri;
            float py = (float)hi + qy*ri;
            float x0f = floorf(px), y0f = floorf(py);
            float ffx = px - x0f,   ffy = py - y0f;
            int ix0 = (int)x0f, iy0 = (int)y0f;
            int bx = min(max(ix0, 0), WN-2);
            int by = min(max(iy0, 0), HN-2);
            float wx0 = 1.f - ffx, wx1 = ffx;
            float wy0 = 1.f - ffy, wy1 = ffy;
            float sxL = (ix0   == bx   ? wx0 : 0.f) + (ix0+1 == bx   ? wx1 : 0.f);
            float sxR = (ix0   == bx+1 ? wx0 : 0.f) + (ix0+1 == bx+1 ? wx1 : 0.f);
            float syT = (iy0   == by   ? wy0 : 0.f) + (iy0+1 == by   ? wy1 : 0.f);
            float syB = (iy0   == by+1 ? wy0 : 0.f) + (iy0+1 == by+1 ? wy1 : 0.f);
            int e = bp*NT + n;
            tapB[e] = (by*WN + bx)*CN;
            tapW[e] = make_float4(syT*sxL, syT*sxR, syB*sxL, syB*sxR);
        }
    }
    __syncthreads();   // cheap one-time safety; taps are wave-private anyway

    const int q    = lane >> 4;
    const int m15  = lane & 15;
    const int mpix = g*16 + m15;

    floatx4 acc[4];
    #pragma unroll
    for (int f = 0; f < 4; ++f) acc[f] = (floatx4){0.f,0.f,0.f,0.f};

    // ---- 9 phases: bf16 gather (wave-private sT) + MFMA, no barriers
    for (int n = 0; n < NT; ++n) {
        #pragma unroll
        for (int i = 0; i < 2; ++i) {
            int bp = g*16 + i*8 + p8;
            int e  = bp*NT + n;
            int tb = tapB[e];
            float4 tw = tapW[e];
            const unsigned short* A = xb + tb + c8*8;
            bf16x8 v00 = *(const bf16x8*)A;
            bf16x8 v01 = *(const bf16x8*)(A + CN);
            bf16x8 v10 = *(const bf16x8*)(A + WN*CN);
            bf16x8 v11 = *(const bf16x8*)(A + WN*CN + CN);
            unsigned int pk[4];
            #pragma unroll
            for (int j = 0; j < 8; j += 2) {
                float a0 = fmaf(tw.x, bf2f(v00[j]),
                           fmaf(tw.y, bf2f(v01[j]),
                           fmaf(tw.z, bf2f(v10[j]), tw.w*bf2f(v11[j]))));
                float a1 = fmaf(tw.x, bf2f(v00[j+1]),
                           fmaf(tw.y, bf2f(v01[j+1]),
                           fmaf(tw.z, bf2f(v10[j+1]), tw.w*bf2f(v11[j+1]))));
                pk[j>>1] = (unsigned int)f2bf(a0) | ((unsigned int)f2bf(a1)<<16);
            }
            *(int4*)&sT[bp*72 + c8*8] = make_int4(pk[0],pk[1],pk[2],pk[3]);
        }
        #pragma unroll
        for (int k0 = 0; k0 < 64; k0 += 32) {
            bf16x8 a = *(const bf16x8*)&sT[mpix*72 + k0 + q*8];
            #pragma unroll
            for (int f = 0; f < 4; ++f) {
                bf16x8 bfr = *(const bf16x8*)&wbf[((size_t)(n*ON + f*16 + m15))*CN + k0 + q*8];
                acc[f] = __builtin_amdgcn_mfma_f32_16x16x32_bf16(a, bfr, acc[f], 0, 0, 0);
            }
        }
    }

    // ---- epilogue: transpose through LDS for coalesced stores
    __syncthreads();
    float* tr = (float*)lds;             // [64 o][72 pix] overlays dead regions
    #pragma unroll
    for (int f = 0; f < 4; ++f) {
        int o = f*16 + m15;
        #pragma unroll
        for (int r = 0; r < 4; ++r) {
            int pix = g*16 + q*4 + r;    // C/D layout: row=(lane>>4)*4+reg
            tr[o*72 + pix] = acc[f][r];
        }
    }
    __syncthreads();
    const int og = tid >> 6;
    float* ob = out + (((size_t)bi*ON)*HN + hi)*WN + w0;
    #pragma unroll
    for (int j = 0; j < 16; ++j) {
        int o = og*16 + j;
        ob[(size_t)o*HWN + lane] = tr[o*72 + lane];
    }
}

// ---------------------------------------------------------------------------
extern "C" void kernel_launch(void* const* d_in, const int* in_sizes, int n_in,
                              void* d_out, int out_size, void* d_ws, size_t ws_size,
                              hipStream_t stream) {
    const float* x      = (const float*)d_in[0];
    const float* w_off  = (const float*)d_in[1];
    const float* w_conv = (const float*)d_in[2];
    const float* P      = (const float*)d_in[3];
    const float* d      = (const float*)d_in[4];
    const float* Pinv   = (const float*)d_in[5];
    float* out = (float*)d_out;

    const size_t XTH_BYTES = (size_t)BN*HN*WN*CN*2;   // 8388608
    unsigned short* xTh = (unsigned short*)d_ws;
    unsigned short* wbf = (unsigned short*)((char*)d_ws + XTH_BYTES);

    transpose_kernel<<<1024, 256, 0, stream>>>(x, xTh);
    wbf_kernel<<<144, 256, 0, stream>>>(w_conv, wbf);
    fused_deform<<<1024, 256, 0, stream>>>(xTh, w_off, P, d, Pinv, wbf, out);
}